// Round 2
// baseline (181.372 us; speedup 1.0000x reference)
//
#include <hip/hip_runtime.h>

#define LEN 256
#define NT 8
#define PAD 256
#define XSTRIDE (PAD + LEN)   // 512 floats per t-row, pow2 for cheap indexing

// One block computes a 64x64 tile of TM for one batch b, summed over all T=8
// signals. x[b,t,:] staged in LDS with 256 zeros in front so x[n-l] is a
// plain LDS read at [PAD + n - l] (causal zero-padding for free).
//
// Inner loop uses ROLLING float4 windows: the high half of each A/B fragment
// at group g becomes the low half at group g+1, so only 3 ds_read_b128 per
// group (xn, a_next, b_next) instead of 5 -> LDS 288 cyc/CU/group < VALU 320,
// i.e. VALU-bound.
__global__ __launch_bounds__(256, 2) void bispec_kernel(const float* __restrict__ x,
                                                        float* __restrict__ out) {
    __shared__ float xs[NT * XSTRIDE];
    const int b = blockIdx.z;
    const int tid = threadIdx.x;

    // Stage: 8 * 512 floats, 16 per thread. j<PAD -> zero pad, else signal.
    const float* xb = x + b * (NT * LEN);
    #pragma unroll
    for (int i = tid; i < NT * XSTRIDE; i += 256) {
        const int t = i >> 9;             // /XSTRIDE
        const int j = i & (XSTRIDE - 1);  // %XSTRIDE
        xs[i] = (j < PAD) ? 0.0f : xb[t * LEN + (j - PAD)];
    }
    __syncthreads();

    const int r = tid >> 4;   // 0..15
    const int c = tid & 15;   // 0..15
    const int l1 = (blockIdx.x << 6) + (r << 2);  // multiple of 4
    const int l2 = (blockIdx.y << 6) + (c << 2);  // multiple of 4

    float acc[4][4] = {{0.f, 0.f, 0.f, 0.f},
                       {0.f, 0.f, 0.f, 0.f},
                       {0.f, 0.f, 0.f, 0.f},
                       {0.f, 0.f, 0.f, 0.f}};

    for (int t = 0; t < NT; ++t) {
        const float* xt = &xs[t * XSTRIDE];
        // All three bases are float4-aligned: PAD, l1, l2 are multiples of 4.
        const float4* xn4 = (const float4*)(xt + PAD);           // x[n0 .. n0+3]
        const float4* a4  = (const float4*)(xt + PAD - 4 - l1);  // x[n0-l1-4 .. ]
        const float4* b4  = (const float4*)(xt + PAD - 4 - l2);  // x[n0-l2-4 .. ]

        float4 aprev = a4[0];   // x[n0-l1-4 .. n0-l1-1] for g=0
        float4 bprev = b4[0];

        #pragma unroll 4
        for (int g = 0; g < LEN / 4; ++g) {   // n0 = 4*g
            const float4 xnv = xn4[g];
            const float4 anext = a4[g + 1];   // x[n0-l1 .. n0-l1+3]
            const float4 bnext = b4[g + 1];
            const float av[8] = {aprev.x, aprev.y, aprev.z, aprev.w,
                                 anext.x, anext.y, anext.z, anext.w};
            const float bv[8] = {bprev.x, bprev.y, bprev.z, bprev.w,
                                 bnext.x, bnext.y, bnext.z, bnext.w};
            const float xnk[4] = {xnv.x, xnv.y, xnv.z, xnv.w};
            #pragma unroll
            for (int k = 0; k < 4; ++k) {   // n = n0 + k
                // A_i = x[n - (l1+i)] = av[4 + k - i]  (static index after unroll)
                float p[4];
                #pragma unroll
                for (int i = 0; i < 4; ++i) p[i] = xnk[k] * av[4 + k - i];
                #pragma unroll
                for (int j = 0; j < 4; ++j) {
                    const float bj = bv[4 + k - j];
                    #pragma unroll
                    for (int i = 0; i < 4; ++i) acc[i][j] = fmaf(p[i], bj, acc[i][j]);
                }
            }
            aprev = anext;
            bprev = bnext;
        }
    }

    // Epilogue: mean over T and /L  ->  * 1/2048. float4 stores.
    const float scale = 1.0f / (float)(LEN * NT);
    float* ob = out + (size_t)b * LEN * LEN + (size_t)l1 * LEN + l2;
    #pragma unroll
    for (int i = 0; i < 4; ++i) {
        float4 v;
        v.x = acc[i][0] * scale;
        v.y = acc[i][1] * scale;
        v.z = acc[i][2] * scale;
        v.w = acc[i][3] * scale;
        *(float4*)(ob + (size_t)i * LEN) = v;
    }
}

extern "C" void kernel_launch(void* const* d_in, const int* in_sizes, int n_in,
                              void* d_out, int out_size, void* d_ws, size_t ws_size,
                              hipStream_t stream) {
    const float* x = (const float*)d_in[0];   // [32, 8, 256] fp32
    float* out = (float*)d_out;               // [32*256*256] source ++ [32*8*256] target

    dim3 grid(4, 4, 32);   // (l1 tiles, l2 tiles, batch)
    bispec_kernel<<<grid, dim3(256), 0, stream>>>(x, out);

    // Second tuple element: target passed through unchanged.
    hipMemcpyAsync(out + (size_t)32 * LEN * LEN, x,
                   (size_t)32 * NT * LEN * sizeof(float),
                   hipMemcpyDeviceToDevice, stream);
}

// Round 3
// 91.090 us; speedup vs baseline: 1.9911x; 1.9911x over previous
//
#include <hip/hip_runtime.h>

// Bispectrum via 3-pass bf16 MFMA emulation (AhBh + AhBl + AlBh ~ fp32 GEMM).
// TM_b = S diag(x) S^T, per-batch M=N=256, K=T*L=2048.
//
// Layout note: MFMA pairs A-slot(lane-group g, reg-elem j) with the matching
// B-slot, so the k<->slot bijection is ours to choose; we use k = g*8 + j on
// BOTH sides, which makes every gather 8 consecutive elements. Only HW-fixed
// facts used: A-row/B-col = lane&15; C/D col = lane&15, row = (lane>>4)*4+reg.
//
// LDS holds TWO copies of the packed bf16-split signal (P[n] = hi | lo<<16),
// copy1 shifted by +1 dword, so any 8-consecutive window can be read as four
// 8B-aligned ds_read_b64 regardless of parity. 256-zero left pad per t gives
// x[n-l]=0 for free. No barriers in the main loop; wave w accumulates t={w,w+4},
// then a 2-stage LDS tree reduction combines the 4 waves.

typedef short bf16x8 __attribute__((ext_vector_type(8)));
typedef float f32x4 __attribute__((ext_vector_type(4)));

#define LEN 256
#define NT 8

static __device__ __forceinline__ bf16x8 mk8(uint a0, uint a1, uint a2, uint a3) {
    union { uint u[4]; bf16x8 v; } c;
    c.u[0] = a0; c.u[1] = a1; c.u[2] = a2; c.u[3] = a3;
    return c.v;
}

// fp32 -> packed (bf16_hi | bf16_lo << 16), both halves RNE-rounded
static __device__ __forceinline__ uint packsplit(float v) {
    uint u  = __float_as_uint(v);
    uint hb = (u + 0x7fffu + ((u >> 16) & 1u)) >> 16;
    float hf = __uint_as_float(hb << 16);
    float lf = v - hf;
    uint lb = __float_as_uint(lf);
    uint lo = (lb + 0x7fffu + ((lb >> 16) & 1u)) >> 16;
    return hb | (lo << 16);
}

// packed -> fp32 (hi + lo), error ~2^-17 relative
static __device__ __forceinline__ float unpackf(uint p) {
    return __uint_as_float(p << 16) + __uint_as_float(p & 0xffff0000u);
}

__global__ __launch_bounds__(256, 2) void bispec_mfma(const float* __restrict__ x,
                                                      float* __restrict__ out) {
    __shared__ uint smem[8704];   // 34816 B: P0[0..4095], P1 at 4097+i; reused for reduction

    const int b   = blockIdx.z;
    const int tid = threadIdx.x;
    const int w   = tid >> 6;     // wave 0..3
    const int l   = tid & 63;
    const int cg  = l & 15;       // A-row / B-col within a 16x16 fragment
    const int g   = l >> 4;       // k-group
    const int l1b = blockIdx.x << 6;
    const int l2b = blockIdx.y << 6;

    // ---- init: packed split copies. Layout per t: [t*512 .. +255]=0 pad, [+256..+511]=x[t] ----
    const float* xb = x + b * (NT * LEN);
    for (int i = tid; i < 4096; i += 256) {   // exactly 16 iterations
        int j = i & 511;
        float v = (j >= 256) ? xb[(i >> 9) * 256 + (j - 256)] : 0.0f;
        uint p = packsplit(v);
        smem[i]        = p;   // P0[i]   = X[i]
        smem[4097 + i] = p;   // P1[i+1] = X[i]  (copy shifted +1 for odd-parity b64 reads)
    }
    __syncthreads();

    f32x4 acc[4][4];
    #pragma unroll
    for (int mi = 0; mi < 4; ++mi)
        #pragma unroll
        for (int ni = 0; ni < 4; ++ni)
            acc[mi][ni] = 0.0f;

    for (int tt = 0; tt < 2; ++tt) {
        const int t   = w + tt * 4;        // wave w handles t = {w, w+4}
        const int tB  = t * 512 + 256;     // position of n=0
        const int qA0 = tB + g * 8 - l1b - cg;
        const int qB0 = tB + g * 8 - l2b - cg;
        const int xnb = tB + g * 8;

        for (int kb = 0; kb < 8; ++kb) {   // K-chunk of 32 per t
            // x[n] octet, n = kb*32 + g*8 + j (16B-aligned in P0)
            const uint4 xp0 = *(const uint4*)&smem[xnb + kb * 32];
            const uint4 xp1 = *(const uint4*)&smem[xnb + kb * 32 + 4];
            const float xn[8] = {unpackf(xp0.x), unpackf(xp0.y), unpackf(xp0.z), unpackf(xp0.w),
                                 unpackf(xp1.x), unpackf(xp1.y), unpackf(xp1.z), unpackf(xp1.w)};

            uint Ah[4][4], Al[4][4], Bh[4][4], Bl[4][4];

            // A fragments: A[row][k] = x[n] * x[n - row_abs], split into hi/lo
            #pragma unroll
            for (int mi = 0; mi < 4; ++mi) {
                int q0 = qA0 + kb * 32 - mi * 16;        // window start (x[q0..q0+7])
                int ad = q0 + (q0 & 1) * 4097;           // parity-aligned copy select
                const uint2 d0 = *(const uint2*)&smem[ad];
                const uint2 d1 = *(const uint2*)&smem[ad + 2];
                const uint2 d2 = *(const uint2*)&smem[ad + 4];
                const uint2 d3 = *(const uint2*)&smem[ad + 6];
                const uint sd[8] = {d0.x, d0.y, d1.x, d1.y, d2.x, d2.y, d3.x, d3.y};
                #pragma unroll
                for (int p = 0; p < 4; ++p) {
                    float a0 = xn[2*p]     * unpackf(sd[2*p]);
                    float a1 = xn[2*p + 1] * unpackf(sd[2*p + 1]);
                    uint u0 = __float_as_uint(a0);
                    uint h0 = (u0 + 0x7fffu + ((u0 >> 16) & 1u)) >> 16;
                    uint u1 = __float_as_uint(a1);
                    uint h1 = (u1 + 0x7fffu + ((u1 >> 16) & 1u)) >> 16;
                    Ah[mi][p] = h0 | (h1 << 16);
                    float e0 = a0 - __uint_as_float(h0 << 16);
                    float e1 = a1 - __uint_as_float(h1 << 16);
                    Al[mi][p] = (__float_as_uint(e0) >> 16) | (__float_as_uint(e1) & 0xffff0000u);
                }
            }

            // B fragments: B[k][col] = x[n - col_abs] — direct gather of packed split
            #pragma unroll
            for (int ni = 0; ni < 4; ++ni) {
                int p0 = qB0 + kb * 32 - ni * 16;
                int ad = p0 + (p0 & 1) * 4097;
                const uint2 d0 = *(const uint2*)&smem[ad];
                const uint2 d1 = *(const uint2*)&smem[ad + 2];
                const uint2 d2 = *(const uint2*)&smem[ad + 4];
                const uint2 d3 = *(const uint2*)&smem[ad + 6];
                Bh[ni][0] = (d0.x & 0xffffu) | (d0.y << 16);
                Bl[ni][0] = (d0.x >> 16)     | (d0.y & 0xffff0000u);
                Bh[ni][1] = (d1.x & 0xffffu) | (d1.y << 16);
                Bl[ni][1] = (d1.x >> 16)     | (d1.y & 0xffff0000u);
                Bh[ni][2] = (d2.x & 0xffffu) | (d2.y << 16);
                Bl[ni][2] = (d2.x >> 16)     | (d2.y & 0xffff0000u);
                Bh[ni][3] = (d3.x & 0xffffu) | (d3.y << 16);
                Bl[ni][3] = (d3.x >> 16)     | (d3.y & 0xffff0000u);
            }

            // 3-pass MFMA: AhBh + AhBl + AlBh
            #pragma unroll
            for (int mi = 0; mi < 4; ++mi) {
                const bf16x8 ah = mk8(Ah[mi][0], Ah[mi][1], Ah[mi][2], Ah[mi][3]);
                const bf16x8 al = mk8(Al[mi][0], Al[mi][1], Al[mi][2], Al[mi][3]);
                #pragma unroll
                for (int ni = 0; ni < 4; ++ni) {
                    const bf16x8 bh = mk8(Bh[ni][0], Bh[ni][1], Bh[ni][2], Bh[ni][3]);
                    const bf16x8 bl = mk8(Bl[ni][0], Bl[ni][1], Bl[ni][2], Bl[ni][3]);
                    acc[mi][ni] = __builtin_amdgcn_mfma_f32_16x16x32_bf16(ah, bh, acc[mi][ni], 0, 0, 0);
                    acc[mi][ni] = __builtin_amdgcn_mfma_f32_16x16x32_bf16(ah, bl, acc[mi][ni], 0, 0, 0);
                    acc[mi][ni] = __builtin_amdgcn_mfma_f32_16x16x32_bf16(al, bh, acc[mi][ni], 0, 0, 0);
                }
            }
        }
    }

    // ---- cross-wave reduction over t-partials (LDS reused; stride 68 kills bank conflicts) ----
    __syncthreads();
    float* red0 = (float*)smem;            // 4352 dwords
    float* red1 = (float*)(smem + 4352);   // 4352 dwords

    if (w == 2) {
        #pragma unroll
        for (int mi = 0; mi < 4; ++mi)
            #pragma unroll
            for (int ni = 0; ni < 4; ++ni)
                #pragma unroll
                for (int q = 0; q < 4; ++q)
                    red0[(mi*16 + g*4 + q)*68 + ni*16 + cg] = acc[mi][ni][q];
    }
    if (w == 3) {
        #pragma unroll
        for (int mi = 0; mi < 4; ++mi)
            #pragma unroll
            for (int ni = 0; ni < 4; ++ni)
                #pragma unroll
                for (int q = 0; q < 4; ++q)
                    red1[(mi*16 + g*4 + q)*68 + ni*16 + cg] = acc[mi][ni][q];
    }
    __syncthreads();
    if (w == 0) {
        #pragma unroll
        for (int mi = 0; mi < 4; ++mi)
            #pragma unroll
            for (int ni = 0; ni < 4; ++ni)
                #pragma unroll
                for (int q = 0; q < 4; ++q)
                    acc[mi][ni][q] += red0[(mi*16 + g*4 + q)*68 + ni*16 + cg];
    }
    if (w == 1) {
        #pragma unroll
        for (int mi = 0; mi < 4; ++mi)
            #pragma unroll
            for (int ni = 0; ni < 4; ++ni)
                #pragma unroll
                for (int q = 0; q < 4; ++q)
                    acc[mi][ni][q] += red1[(mi*16 + g*4 + q)*68 + ni*16 + cg];
    }
    __syncthreads();
    if (w == 1) {
        #pragma unroll
        for (int mi = 0; mi < 4; ++mi)
            #pragma unroll
            for (int ni = 0; ni < 4; ++ni)
                #pragma unroll
                for (int q = 0; q < 4; ++q)
                    red0[(mi*16 + g*4 + q)*68 + ni*16 + cg] = acc[mi][ni][q];
    }
    __syncthreads();
    if (w == 0) {
        const float s = 1.0f / (float)(LEN * NT);   // 1/2048
        float* ob = out + (size_t)b * LEN * LEN;
        #pragma unroll
        for (int mi = 0; mi < 4; ++mi)
            #pragma unroll
            for (int ni = 0; ni < 4; ++ni)
                #pragma unroll
                for (int q = 0; q < 4; ++q) {
                    float v = acc[mi][ni][q] + red0[(mi*16 + g*4 + q)*68 + ni*16 + cg];
                    ob[(size_t)(l1b + mi*16 + g*4 + q) * LEN + (l2b + ni*16 + cg)] = v * s;
                }
    }
}

extern "C" void kernel_launch(void* const* d_in, const int* in_sizes, int n_in,
                              void* d_out, int out_size, void* d_ws, size_t ws_size,
                              hipStream_t stream) {
    const float* x = (const float*)d_in[0];   // [32, 8, 256] fp32
    float* out = (float*)d_out;               // [32*256*256] source ++ [32*8*256] target

    dim3 grid(4, 4, 32);   // (l1 tiles, l2 tiles, batch)
    bispec_mfma<<<grid, dim3(256), 0, stream>>>(x, out);

    // Second tuple element: target passed through unchanged.
    hipMemcpyAsync(out + (size_t)32 * LEN * LEN, x,
                   (size_t)32 * NT * LEN * sizeof(float),
                   hipMemcpyDeviceToDevice, stream);
}

// Round 8
// 88.990 us; speedup vs baseline: 2.0381x; 1.0236x over previous
//
#include <hip/hip_runtime.h>

// Bispectrum TM_b = S diag(x) S^T via 2-term fp16-split MFMA emulation
// (AhBh + AhBl + AlBh), with:
//  - triangle-only tiles (TM symmetric) + zero-chunk skip (n >= max(l1,l2)),
//    split into 20 exactly-equal-work blocks per batch -> partials in d_ws,
//    reduce kernel sums + mirrors. 3.2x less work than full grid.
//  - fp32 signal staged in LDS twice: copy1 offset 4113 (odd => b64-aligned
//    reads for odd window starts; ==17 mod 32 => no systematic bank clash).
//  - fp16 split via v_cvt_pkrtz (1-op pair pack); residual ~2^-22/term.
// MFMA facts used (HW-verified m89 + round-3 pass): A-row/B-col = lane&15;
// k<->slot bijection identical for A and B (we use k = g*8 + j on both sides);
// C/D col = lane&15, row = (lane>>4)*4 + reg.

#define LEN 256
#define NT 8
#define F1OFF 4113      // parity copy base (odd, ==17 mod 32)
#define REDSTR 68       // reduction buffer stride (16B-aligned cols, balanced banks)
#define SMEM_DW 8704    // max(F: 4113+4096=8209, red: 2*64*68=8704)

typedef _Float16 f16x8 __attribute__((ext_vector_type(8)));
typedef float    f32x4 __attribute__((ext_vector_type(4)));

// 20 equal-work blocks per batch: {i, j, kb0, _}; kbn = 2 always.
__constant__ uchar4 kBlockTab[20] = {
    {0,0,0,0},{0,0,2,0},{0,0,4,0},{0,0,6,0},
    {1,0,2,0},{1,0,4,0},{1,0,6,0},
    {1,1,2,0},{1,1,4,0},{1,1,6,0},
    {2,0,4,0},{2,0,6,0},
    {2,1,4,0},{2,1,6,0},
    {2,2,4,0},{2,2,6,0},
    {3,0,6,0},{3,1,6,0},{3,2,6,0},{3,3,6,0}};
// 10 tile-pairs: {i, j, slot_base, slot_count}
__constant__ uchar4 kPairTab[10] = {
    {0,0,0,4},{1,0,4,3},{1,1,7,3},{2,0,10,2},{2,1,12,2},{2,2,14,2},
    {3,0,16,1},{3,1,17,1},{3,2,18,1},{3,3,19,1}};

// split a pair of f32 into (fp16 hi pair bits, fp16 residual pair bits).
// auto-deduced builtin return type + memcpy bitcast: immune to the exact
// __fp16/_Float16 vector spelling (round-6 compile failure).
static __device__ __forceinline__ void split2(float a0, float a1, uint& hb, uint& lb) {
    auto h = __builtin_amdgcn_cvt_pkrtz(a0, a1);
    float e0 = a0 - (float)h[0];
    float e1 = a1 - (float)h[1];
    auto e = __builtin_amdgcn_cvt_pkrtz(e0, e1);
    __builtin_memcpy(&hb, &h, 4);
    __builtin_memcpy(&lb, &e, 4);
}
static __device__ __forceinline__ f16x8 mkf(const uint* u) {
    f16x8 v;
    __builtin_memcpy(&v, u, 16);
    return v;
}
// 8 consecutive padded-signal floats starting at (possibly odd) dword p0.
static __device__ __forceinline__ void readwin(const float* fs, int p0, float* wv) {
    const float* bp = fs + p0 + ((p0 & 1) ? F1OFF : 0);
    float2 d0 = *(const float2*)bp;
    float2 d1 = *(const float2*)(bp + 2);
    float2 d2 = *(const float2*)(bp + 4);
    float2 d3 = *(const float2*)(bp + 6);
    wv[0] = d0.x; wv[1] = d0.y; wv[2] = d1.x; wv[3] = d1.y;
    wv[4] = d2.x; wv[5] = d2.y; wv[6] = d3.x; wv[7] = d3.y;
}

__global__ __launch_bounds__(256, 3) void bispec_main(const float* __restrict__ x,
                                                      float* __restrict__ dst,
                                                      int partial) {
    __shared__ float fs[SMEM_DW];
    const int b  = blockIdx.y;
    const int bx = blockIdx.x;

    int ti, tj, kb0, kbn;
    if (partial) {
        uchar4 e = kBlockTab[bx];
        ti = e.x; tj = e.y; kb0 = e.z; kbn = 2;
    } else {
        ti = bx >> 2; tj = bx & 3;
        int m = ti > tj ? ti : tj;
        kb0 = 2 * m; kbn = 8 - 2 * m;
    }
    const int l1b = ti << 6, l2b = tj << 6;
    const int tid = threadIdx.x;
    const int w = tid >> 6, l = tid & 63, cg = l & 15, g = l >> 4;

    // ---- stage padded fp32 signal, two copies (F0 @0, F1 @4113) ----
    const float* xb = x + b * (NT * LEN);
    for (int i = tid; i < 4096; i += 256) {
        int j = i & 511;
        float v = (j >= 256) ? xb[(i >> 9) * 256 + (j - 256)] : 0.0f;
        fs[i] = v;
        fs[F1OFF + i] = v;
    }
    __syncthreads();

    f32x4 acc[4][4];
    #pragma unroll
    for (int mi = 0; mi < 4; ++mi)
        #pragma unroll
        for (int ni = 0; ni < 4; ++ni) acc[mi][ni] = 0.0f;

    for (int tt = 0; tt < 2; ++tt) {
        const int t  = w + tt * 4;           // wave w covers t = {w, w+4}
        const int tB = t * 512 + 256;        // padded index of n=0
        const int cA = tB + g * 8 - l1b - cg;
        const int cB = tB + g * 8 - l2b - cg;
        const int cX = tB + g * 8;

        for (int kb = kb0; kb < kb0 + kbn; ++kb) {
            const float4 x0 = *(const float4*)&fs[cX + kb * 32];
            const float4 x1 = *(const float4*)&fs[cX + kb * 32 + 4];
            const float xn[8] = {x0.x, x0.y, x0.z, x0.w, x1.x, x1.y, x1.z, x1.w};

            // A fragments: split(x[n] * x[n-row]) for 4 row-blocks
            f16x8 ah[4], al[4];
            #pragma unroll
            for (int mi = 0; mi < 4; ++mi) {
                float wv[8];
                readwin(fs, cA + kb * 32 - mi * 16, wv);
                uint Ahp[4], Alp[4];
                #pragma unroll
                for (int p = 0; p < 4; ++p)
                    split2(xn[2 * p] * wv[2 * p], xn[2 * p + 1] * wv[2 * p + 1],
                           Ahp[p], Alp[p]);
                ah[mi] = mkf(Ahp); al[mi] = mkf(Alp);
            }

            // B fragments: split(x[n-col]); consumed immediately per ni
            #pragma unroll
            for (int ni = 0; ni < 4; ++ni) {
                float wv[8];
                readwin(fs, cB + kb * 32 - ni * 16, wv);
                uint Bhp[4], Blp[4];
                #pragma unroll
                for (int p = 0; p < 4; ++p)
                    split2(wv[2 * p], wv[2 * p + 1], Bhp[p], Blp[p]);
                const f16x8 bh = mkf(Bhp), bl = mkf(Blp);
                #pragma unroll
                for (int mi = 0; mi < 4; ++mi) {
                    acc[mi][ni] = __builtin_amdgcn_mfma_f32_16x16x32_f16(ah[mi], bh, acc[mi][ni], 0, 0, 0);
                    acc[mi][ni] = __builtin_amdgcn_mfma_f32_16x16x32_f16(ah[mi], bl, acc[mi][ni], 0, 0, 0);
                    acc[mi][ni] = __builtin_amdgcn_mfma_f32_16x16x32_f16(al[mi], bh, acc[mi][ni], 0, 0, 0);
                }
            }
        }
    }

    // ---- cross-wave reduction: transposed layout, b128 LDS ops ----
    __syncthreads();
    float* buf0 = fs;
    float* buf1 = fs + 4352;   // 64*68 = 4352
    if (w >= 2) {
        float* bb = (w == 2) ? buf0 : buf1;
        #pragma unroll
        for (int mi = 0; mi < 4; ++mi)
            #pragma unroll
            for (int ni = 0; ni < 4; ++ni)
                *(f32x4*)&bb[(ni * 16 + cg) * REDSTR + mi * 16 + g * 4] = acc[mi][ni];
    }
    __syncthreads();
    if (w < 2) {
        float* bb = (w == 0) ? buf0 : buf1;
        #pragma unroll
        for (int mi = 0; mi < 4; ++mi)
            #pragma unroll
            for (int ni = 0; ni < 4; ++ni)
                acc[mi][ni] += *(f32x4*)&bb[(ni * 16 + cg) * REDSTR + mi * 16 + g * 4];
    }
    __syncthreads();
    if (w == 1) {
        #pragma unroll
        for (int mi = 0; mi < 4; ++mi)
            #pragma unroll
            for (int ni = 0; ni < 4; ++ni)
                *(f32x4*)&buf0[(ni * 16 + cg) * REDSTR + mi * 16 + g * 4] = acc[mi][ni];
    }
    __syncthreads();
    if (w == 0) {
        #pragma unroll
        for (int mi = 0; mi < 4; ++mi)
            #pragma unroll
            for (int ni = 0; ni < 4; ++ni)
                acc[mi][ni] += *(f32x4*)&buf0[(ni * 16 + cg) * REDSTR + mi * 16 + g * 4];

        if (partial) {
            float* ob = dst + ((size_t)b * 20 + bx) * 4096;
            #pragma unroll
            for (int mi = 0; mi < 4; ++mi)
                #pragma unroll
                for (int ni = 0; ni < 4; ++ni)
                    #pragma unroll
                    for (int q = 0; q < 4; ++q)
                        ob[(mi * 16 + g * 4 + q) * 64 + ni * 16 + cg] = acc[mi][ni][q];
        } else {
            float* ob = dst + (size_t)b * (LEN * LEN);
            const float s = 1.0f / (float)(LEN * NT);
            #pragma unroll
            for (int mi = 0; mi < 4; ++mi)
                #pragma unroll
                for (int ni = 0; ni < 4; ++ni)
                    #pragma unroll
                    for (int q = 0; q < 4; ++q)
                        ob[(size_t)(l1b + mi * 16 + g * 4 + q) * LEN + l2b + ni * 16 + cg] =
                            acc[mi][ni][q] * s;
        }
    }
}

// Sum K-split partials, scale, write tile + mirrored tile (TM symmetric).
__global__ __launch_bounds__(256) void bispec_reduce(const float* __restrict__ ws,
                                                     float* __restrict__ out) {
    const int p = blockIdx.x, b = blockIdx.y;
    uchar4 e = kPairTab[p];
    const int ii = e.x, jj = e.y, s = e.z, c = e.w;
    const float* base = ws + ((size_t)b * 20 + s) * 4096;
    float* ob = out + (size_t)b * (LEN * LEN);
    const float scale = 1.0f / (float)(LEN * NT);
    for (int k = threadIdx.x; k < 4096; k += 256) {
        float v = base[k];
        for (int q = 1; q < c; ++q) v += base[(size_t)q * 4096 + k];
        v *= scale;
        int r = k >> 6, cc = k & 63;
        ob[(ii * 64 + r) * LEN + jj * 64 + cc] = v;
        if (ii != jj) ob[(jj * 64 + cc) * LEN + ii * 64 + r] = v;
    }
}

extern "C" void kernel_launch(void* const* d_in, const int* in_sizes, int n_in,
                              void* d_out, int out_size, void* d_ws, size_t ws_size,
                              hipStream_t stream) {
    const float* x = (const float*)d_in[0];   // [32, 8, 256] fp32
    float* out = (float*)d_out;               // [32*256*256] source ++ [32*8*256] target

    const size_t ws_need = (size_t)32 * 20 * 4096 * sizeof(float);  // 10.5 MB
    if (ws_size >= ws_need) {
        float* ws = (float*)d_ws;
        bispec_main<<<dim3(20, 32), dim3(256), 0, stream>>>(x, ws, 1);
        bispec_reduce<<<dim3(10, 32), dim3(256), 0, stream>>>(ws, out);
    } else {
        bispec_main<<<dim3(16, 32), dim3(256), 0, stream>>>(x, out, 0);
    }

    // Second tuple element: target passed through unchanged.
    (void)hipMemcpyAsync(out + (size_t)32 * LEN * LEN, x,
                         (size_t)32 * NT * LEN * sizeof(float),
                         hipMemcpyDeviceToDevice, stream);
}